// Round 1
// baseline (309.716 us; speedup 1.0000x reference)
//
#include <hip/hip_runtime.h>
#include <stdint.h>

// Problem constants
#define F_     128
#define N_     12288
#define NH_    9
#define NSLOT_ 8
#define NVARS_ 8
#define NUP_   (4*N_)
#define K6_    (NH_*F_)   // 1152
#define NC6_   1024

typedef __attribute__((ext_vector_type(8))) short bf16x8;
typedef __attribute__((ext_vector_type(4))) float f32x4;

typedef const __attribute__((address_space(1))) unsigned char* gp1_t;
typedef __attribute__((address_space(3))) unsigned char* lp3_t;

__device__ __forceinline__ void load16(const void* g, void* l) {
  __builtin_amdgcn_global_load_lds((gp1_t)g, (lp3_t)l, 16, 0, 0);
}

__device__ __forceinline__ unsigned short f2bf(float f) {
  union { float f; unsigned int u; } x; x.f = f;
  unsigned int u = x.u;
  unsigned int r = u + 0x7FFFu + ((u >> 16) & 1u);   // RNE
  return (unsigned short)(r >> 16);
}

// ---------------- converts ----------------
__global__ void k_conv_emb(const float4* __restrict__ src, ushort4* __restrict__ dst, int n4) {
  int i = blockIdx.x * blockDim.x + threadIdx.x;
  if (i >= n4) return;
  float4 v = src[i];
  ushort4 o;
  o.x = f2bf(v.x); o.y = f2bf(v.y); o.z = f2bf(v.z); o.w = f2bf(v.w);
  dst[i] = o;
}

// dst[j*rows + k] = bf16(src[k*cols + j]) ; dst is [cols][rows]
__global__ void k_transpose_bf(const float* __restrict__ src, unsigned short* __restrict__ dst,
                               int rows, int cols) {
  int i = blockIdx.x * blockDim.x + threadIdx.x;
  if (i >= rows * cols) return;
  int j = i / rows, k = i % rows;
  dst[i] = f2bf(src[k * cols + j]);
}

// ---------------- zoom 5: h5 = e5 @ W5 + b5 ; y5 = x5*scale + shift ----------------
// block: 64 rows x 256 cols (full 2F), 256 thr (4 waves: 2 wr x 2 wc), BK=64, 2 k-steps
__global__ __launch_bounds__(256) void k_h5(
    const unsigned short* __restrict__ embB,   // [NVARS][N][F] bf16
    const unsigned short* __restrict__ W5T,    // [256][128]  bf16 (transposed W5)
    const float* __restrict__ b5,              // [256]
    const float* __restrict__ x5,              // [NSLOT][N][F]
    const int* __restrict__ var_idx,           // [NSLOT]
    const int* __restrict__ adjc,              // [N][9]
    float* __restrict__ y5)                    // [NSLOT][N][F]
{
  __shared__ __align__(1024) unsigned char smem[8192 + 32768 + 64*4];
  unsigned char* Asm = smem;                 // 64 rows x 128 B (swizzled)
  unsigned char* Bsm = smem + 8192;          // 256 rows x 128 B (swizzled)
  int* ald = (int*)(smem + 8192 + 32768);

  const int tid = threadIdx.x;
  const int l = tid & 63, w = tid >> 6;
  const int wr = w >> 1, wc = w & 1;
  const int li8 = l >> 3, pc = l & 7, l15 = l & 15, l16 = l >> 4;

  const int nt = blockIdx.x, slot = blockIdx.y;
  const int n0 = nt * 64;
  const int var = var_idx[slot];

  if (tid < 64) ald[tid] = adjc[(n0 + tid) * NH_];   // self index (col 0)
  __syncthreads();

  const f32x4 fz = {0.f, 0.f, 0.f, 0.f};
  f32x4 accS[2][4], accH[2][4];
#pragma unroll
  for (int mf = 0; mf < 2; ++mf)
#pragma unroll
    for (int nf = 0; nf < 4; ++nf) { accS[mf][nf] = fz; accH[mf][nf] = fz; }

  const size_t embVarOff = (size_t)var * ((size_t)N_ * F_);

  for (int step = 0; step < 2; ++step) {
    const int k0 = step << 6;
    // stage A: 8 chunks of 1KB, 2 per wave. lane i -> row q*8+i/8, phys chunk i%8
#pragma unroll
    for (int q2 = 0; q2 < 2; ++q2) {
      const int q = w * 2 + q2;
      const int r = q * 8 + li8;
      const int lc = pc ^ (r & 7);               // pre-swizzled source chunk
      const unsigned short* g = embB + embVarOff + (size_t)ald[r] * F_ + k0 + lc * 8;
      load16(g, Asm + q * 1024);
    }
    // stage B: 32 chunks, 8 per wave
#pragma unroll
    for (int q2 = 0; q2 < 8; ++q2) {
      const int q = w * 8 + q2;
      const int j = q * 8 + li8;
      const int lc = pc ^ (j & 7);
      const unsigned short* g = W5T + (size_t)j * F_ + k0 + lc * 8;
      load16(g, Bsm + q * 1024);
    }
    __syncthreads();

#pragma unroll
    for (int kf = 0; kf < 2; ++kf) {
      const int kc = kf * 4 + l16;               // logical 16B chunk along K
      bf16x8 a[2], bs[4], bh[4];
#pragma unroll
      for (int mf = 0; mf < 2; ++mf) {
        const int r = wr * 32 + mf * 16 + l15;
        a[mf] = *(const bf16x8*)(Asm + r * 128 + ((kc ^ (r & 7)) << 4));
      }
#pragma unroll
      for (int nf = 0; nf < 4; ++nf) {
        const int js = wc * 64 + nf * 16 + l15;        // scale col
        bs[nf] = *(const bf16x8*)(Bsm + js * 128 + ((kc ^ (js & 7)) << 4));
        const int jh = js + 128;                       // shift col
        bh[nf] = *(const bf16x8*)(Bsm + jh * 128 + ((kc ^ (jh & 7)) << 4));
      }
#pragma unroll
      for (int mf = 0; mf < 2; ++mf)
#pragma unroll
        for (int nf = 0; nf < 4; ++nf) {
          accS[mf][nf] = __builtin_amdgcn_mfma_f32_16x16x32_bf16(a[mf], bs[nf], accS[mf][nf], 0, 0, 0);
          accH[mf][nf] = __builtin_amdgcn_mfma_f32_16x16x32_bf16(a[mf], bh[nf], accH[mf][nf], 0, 0, 0);
        }
    }
    __syncthreads();
  }

  // epilogue: FiLM
#pragma unroll
  for (int mf = 0; mf < 2; ++mf)
#pragma unroll
    for (int nf = 0; nf < 4; ++nf) {
      const int f = wc * 64 + nf * 16 + l15;
      const float sb = b5[f];
      const float hb = b5[128 + f];
#pragma unroll
      for (int reg = 0; reg < 4; ++reg) {
        const int r = wr * 32 + mf * 16 + l16 * 4 + reg;   // C/D: row=(l>>4)*4+reg
        const int n = n0 + r;
        const size_t idx = ((size_t)slot * N_ + n) * F_ + f;
        y5[idx] = x5[idx] * (accS[mf][nf][reg] + sb) + (accH[mf][nf][reg] + hb);
      }
    }
}

// ---------------- zoom 6: h6 = gather(embs, adjc) @ W6 + b6 ; y6 = x6*scale + shift ----
// block: 128 rows x 256 cols (one child ct), 512 thr (8 waves: 2 wr x 4 wc), BK=64, 18 steps
__global__ __launch_bounds__(512) void k_h6(
    const unsigned short* __restrict__ embB,   // [NVARS][N][F] bf16
    const unsigned short* __restrict__ W6T,    // [1024][1152] bf16 (transposed W6)
    const float* __restrict__ b6,              // [1024]
    const float* __restrict__ x6,              // [NSLOT][NUP][F]
    const int* __restrict__ var_idx,
    const int* __restrict__ adjc,              // [N][9]
    float* __restrict__ y6)                    // [NSLOT][NUP][F]
{
  __shared__ __align__(1024) unsigned char smem[16384 + 32768 + K6_*4];
  unsigned char* Asm = smem;                  // 128 rows x 128 B (swizzled)
  unsigned char* Bsm = smem + 16384;          // 256 rows x 128 B (swizzled)
  int* ald = (int*)(smem + 16384 + 32768);    // 128 x 9 neighbor ids

  const int tid = threadIdx.x;
  const int l = tid & 63, w = tid >> 6;       // 8 waves
  const int wr = w >> 2, wc = w & 3;          // 2 x 4
  const int li8 = l >> 3, pc = l & 7, l15 = l & 15, l16 = l >> 4;

  const int nt = blockIdx.x;                  // 0..95
  const int ct = blockIdx.y;                  // child 0..3
  const int slot = blockIdx.z;                // 0..7
  const int n0 = nt * 128;
  const int col0 = ct * 256;
  const int var = var_idx[slot];

  for (int t = tid; t < 128 * NH_; t += 512) ald[t] = adjc[n0 * NH_ + t];
  __syncthreads();

  const f32x4 fz = {0.f, 0.f, 0.f, 0.f};
  f32x4 accS[4][2], accH[4][2];
#pragma unroll
  for (int mf = 0; mf < 4; ++mf)
#pragma unroll
    for (int nf = 0; nf < 2; ++nf) { accS[mf][nf] = fz; accH[mf][nf] = fz; }

  const size_t embVarOff = (size_t)var * ((size_t)N_ * F_);

  for (int step = 0; step < K6_ / 64; ++step) {   // 18
    const int h = step >> 1;
    const int kk0 = (step & 1) << 6;              // offset within emb row (F=128)
    const int k0 = step << 6;                     // offset within W6T row (K=1152)

    // stage A: 16 chunks, 2 per wave (gathered rows)
#pragma unroll
    for (int q2 = 0; q2 < 2; ++q2) {
      const int q = w * 2 + q2;
      const int r = q * 8 + li8;                  // 0..127
      const int lc = pc ^ (r & 7);
      const int m = ald[r * NH_ + h];
      const unsigned short* g = embB + embVarOff + (size_t)m * F_ + kk0 + lc * 8;
      load16(g, Asm + q * 1024);
    }
    // stage B: 32 chunks, 4 per wave
#pragma unroll
    for (int q2 = 0; q2 < 4; ++q2) {
      const int q = w * 4 + q2;
      const int j = q * 8 + li8;                  // 0..255
      const int lc = pc ^ (j & 7);
      const unsigned short* g = W6T + (size_t)(col0 + j) * K6_ + k0 + lc * 8;
      load16(g, Bsm + q * 1024);
    }
    __syncthreads();

#pragma unroll
    for (int kf = 0; kf < 2; ++kf) {
      const int kc = kf * 4 + l16;
      bf16x8 a[4], bs[2], bh[2];
#pragma unroll
      for (int mf = 0; mf < 4; ++mf) {
        const int r = wr * 64 + mf * 16 + l15;
        a[mf] = *(const bf16x8*)(Asm + r * 128 + ((kc ^ (r & 7)) << 4));
      }
#pragma unroll
      for (int nf = 0; nf < 2; ++nf) {
        const int js = wc * 32 + nf * 16 + l15;
        bs[nf] = *(const bf16x8*)(Bsm + js * 128 + ((kc ^ (js & 7)) << 4));
        const int jh = js + 128;
        bh[nf] = *(const bf16x8*)(Bsm + jh * 128 + ((kc ^ (jh & 7)) << 4));
      }
#pragma unroll
      for (int mf = 0; mf < 4; ++mf)
#pragma unroll
        for (int nf = 0; nf < 2; ++nf) {
          accS[mf][nf] = __builtin_amdgcn_mfma_f32_16x16x32_bf16(a[mf], bs[nf], accS[mf][nf], 0, 0, 0);
          accH[mf][nf] = __builtin_amdgcn_mfma_f32_16x16x32_bf16(a[mf], bh[nf], accH[mf][nf], 0, 0, 0);
        }
    }
    __syncthreads();
  }

  // epilogue: h6 row n reshapes to 4 children x 256; this block owns child ct.
#pragma unroll
  for (int mf = 0; mf < 4; ++mf)
#pragma unroll
    for (int nf = 0; nf < 2; ++nf) {
      const int f = wc * 32 + nf * 16 + l15;
      const float sb = b6[col0 + f];
      const float hb = b6[col0 + 128 + f];
#pragma unroll
      for (int reg = 0; reg < 4; ++reg) {
        const int r = wr * 64 + mf * 16 + l16 * 4 + reg;
        const int nup = 4 * (n0 + r) + ct;
        const size_t idx = ((size_t)slot * NUP_ + nup) * F_ + f;
        y6[idx] = x6[idx] * (accS[mf][nf][reg] + sb) + (accH[mf][nf][reg] + hb);
      }
    }
}

extern "C" void kernel_launch(void* const* d_in, const int* in_sizes, int n_in,
                              void* d_out, int out_size, void* d_ws, size_t ws_size,
                              hipStream_t stream) {
  (void)in_sizes; (void)n_in; (void)out_size; (void)ws_size;
  const float* emb = (const float*)d_in[0];
  const float* x5  = (const float*)d_in[1];
  const float* x6  = (const float*)d_in[2];
  const float* W5  = (const float*)d_in[3];
  const float* b5  = (const float*)d_in[4];
  const float* W6  = (const float*)d_in[5];
  const float* b6  = (const float*)d_in[6];
  const int* var_idx = (const int*)d_in[7];
  const int* adjc    = (const int*)d_in[8];

  float* y5 = (float*)d_out;
  float* y6 = y5 + (size_t)NSLOT_ * N_ * F_;

  unsigned short* embB = (unsigned short*)d_ws;                  // 12,582,912 bf16
  unsigned short* W5T  = embB + (size_t)NVARS_ * N_ * F_;        // 32,768 bf16
  unsigned short* W6T  = W5T + 256 * 128;                        // 1,179,648 bf16

  const int embN4 = NVARS_ * N_ * F_ / 4;
  k_conv_emb<<<(embN4 + 255) / 256, 256, 0, stream>>>((const float4*)emb, (ushort4*)embB, embN4);
  k_transpose_bf<<<(128 * 256 + 255) / 256, 256, 0, stream>>>(W5, W5T, 128, 256);
  k_transpose_bf<<<(1152 * 1024 + 255) / 256, 256, 0, stream>>>(W6, W6T, 1152, 1024);

  k_h5<<<dim3(N_ / 64, NSLOT_), 256, 0, stream>>>(embB, W5T, b5, x5, var_idx, adjc, y5);
  k_h6<<<dim3(N_ / 128, 4, NSLOT_), 512, 0, stream>>>(embB, W6T, b6, x6, var_idx, adjc, y6);
}